// Round 1
// baseline (218.582 us; speedup 1.0000x reference)
//
#include <hip/hip_runtime.h>
#include <math.h>

#define HWSZ 4096   // 64*64
#define DIM  64
#define KCW  512
#define NROW 131072 // 32*4096

// ws layout (floats): ws[0] = loss accumulator; ws[64 .. 64+512) = c_sq
__global__ void vq_prep_kernel(const float* __restrict__ cw, float* __restrict__ ws) {
    int k = blockIdx.x * blockDim.x + threadIdx.x;
    if (k == 0) ws[0] = 0.f;
    if (k < KCW) {
        float s = 0.f;
        #pragma unroll
        for (int d = 0; d < DIM; ++d) { float c = cw[k * DIM + d]; s = fmaf(c, c, s); }
        ws[64 + k] = s;
    }
}

__global__ __launch_bounds__(256) void vq_main_kernel(const float* __restrict__ in,
                                                      const float* __restrict__ cw,
                                                      float* __restrict__ out,
                                                      float* __restrict__ ws) {
    const float* __restrict__ c_sq = ws + 64;
    const int tid = blockIdx.x * 256 + threadIdx.x;
    const int b  = tid >> 12;          // 4096 rows per batch image
    const int hw = tid & (HWSZ - 1);

    const float* __restrict__ xin = in + (size_t)b * (DIM * HWSZ) + hw;
    float x[DIM];
    #pragma unroll
    for (int d = 0; d < DIM; ++d) x[d] = xin[(size_t)d * HWSZ];

    float x_sq = 0.f;
    #pragma unroll
    for (int d = 0; d < DIM; ++d) x_sq = fmaf(x[d], x[d], x_sq);

    float best = INFINITY;
    int bestk = 0;
    for (int k = 0; k < KCW; ++k) {
        const float* __restrict__ c = cw + k * DIM;
        float d0 = 0.f, d1 = 0.f, d2 = 0.f, d3 = 0.f;
        #pragma unroll
        for (int d = 0; d < DIM; d += 4) {
            d0 = fmaf(x[d + 0], c[d + 0], d0);
            d1 = fmaf(x[d + 1], c[d + 1], d1);
            d2 = fmaf(x[d + 2], c[d + 2], d2);
            d3 = fmaf(x[d + 3], c[d + 3], d3);
        }
        float dot = (d0 + d1) + (d2 + d3);
        // mirror reference: (x_sq + c_sq) - 2*dots, fp32 rounding order preserved
        float dist = (x_sq + c_sq[k]) - 2.f * dot;
        if (dist < best) { best = dist; bestk = k; }  // strict <: first index wins ties
    }

    // Gather winning codeword, write quantized output (NCHW) + loss partial.
    const float* __restrict__ q = cw + bestk * DIM;
    float* __restrict__ xout = out + (size_t)b * (DIM * HWSZ) + hw;
    float lsum = 0.f;
    #pragma unroll
    for (int d = 0; d < DIM; ++d) {
        float qd = q[d];
        xout[(size_t)d * HWSZ] = qd;
        float diff = qd - x[d];
        lsum = fmaf(diff, diff, lsum);
    }

    // indices chunk (as float, buffer is f32 throughout)
    out[(size_t)NROW * DIM + tid] = (float)bestk;

    // wave-level reduce then one atomic per wave
    #pragma unroll
    for (int off = 32; off; off >>= 1) lsum += __shfl_down(lsum, off, 64);
    if ((threadIdx.x & 63) == 0) atomicAdd(ws, lsum);
}

__global__ void vq_finalize_kernel(const float* __restrict__ ws, float* __restrict__ out) {
    // loss = (1 + 0.25) * mean((q - x)^2) over B*H*W*D elements
    out[(size_t)NROW * DIM + NROW] = 1.25f * ws[0] / (float)((size_t)NROW * DIM);
}

extern "C" void kernel_launch(void* const* d_in, const int* in_sizes, int n_in,
                              void* d_out, int out_size, void* d_ws, size_t ws_size,
                              hipStream_t stream) {
    const float* in = (const float*)d_in[0];
    const float* cw = (const float*)d_in[1];
    float* out = (float*)d_out;
    float* ws  = (float*)d_ws;

    hipLaunchKernelGGL(vq_prep_kernel, dim3(2), dim3(256), 0, stream, cw, ws);
    hipLaunchKernelGGL(vq_main_kernel, dim3(NROW / 256), dim3(256), 0, stream, in, cw, out, ws);
    hipLaunchKernelGGL(vq_finalize_kernel, dim3(1), dim3(1), 0, stream, ws, out);
}